// Round 1
// baseline (235.681 us; speedup 1.0000x reference)
//
#include <hip/hip_runtime.h>
#include <math.h>

#define D_ 512
#define H_ 8
#define I_ 64
#define L_ 1024

__device__ __forceinline__ float sigmoidf_(float x) { return 1.f / (1.f + expf(-x)); }
__device__ __forceinline__ float siluf_(float x) { return x / (1.f + expf(-x)); }

// ---------------- big GEMM: C[M,N] = A[M,K] @ W[K,N] + bias, fused epilogue ----------------
// mode 0: C = acc+bias
// mode 1: C = silu(acc+bias)
// mode 2: C = (acc+bias) * silu(other[idx])
// mode 3: C = (acc+bias) * other[idx]
#define BM 64
#define BN 64
#define BK 16
#define LDP 68  // padded LDS leading dim (keeps 16B alignment, spreads banks)

__global__ __launch_bounds__(256) void gemm_f32(
    const float* __restrict__ A, const float* __restrict__ W,
    const float* __restrict__ bias, float* __restrict__ C,
    const float* __restrict__ other, int M, int N, int K, int mode)
{
    __shared__ float As[BK][LDP];
    __shared__ float Bs[BK][LDP];
    const int tid = threadIdx.x;
    const int tx = tid & 15, ty = tid >> 4;
    const int row0 = blockIdx.y * BM, col0 = blockIdx.x * BN;
    float acc[4][4] = {};

    for (int k0 = 0; k0 < K; k0 += BK) {
#pragma unroll
        for (int j = 0; j < 4; ++j) {
            int idx = tid + 256 * j;           // 0..1023
            int m = idx >> 4, kk = idx & 15;   // A tile: 64 rows x 16 k
            As[kk][m] = A[(size_t)(row0 + m) * K + (k0 + kk)];
            int n2 = idx & 63, k2 = idx >> 6;  // B tile: 16 k x 64 cols
            Bs[k2][n2] = W[(size_t)(k0 + k2) * N + (col0 + n2)];
        }
        __syncthreads();
#pragma unroll
        for (int k = 0; k < BK; ++k) {
            float ra[4], rb[4];
#pragma unroll
            for (int r = 0; r < 4; ++r) ra[r] = As[k][ty * 4 + r];
#pragma unroll
            for (int r = 0; r < 4; ++r) rb[r] = Bs[k][tx * 4 + r];
#pragma unroll
            for (int i2 = 0; i2 < 4; ++i2)
#pragma unroll
                for (int j2 = 0; j2 < 4; ++j2)
                    acc[i2][j2] = fmaf(ra[i2], rb[j2], acc[i2][j2]);
        }
        __syncthreads();
    }

#pragma unroll
    for (int i2 = 0; i2 < 4; ++i2) {
        int row = row0 + ty * 4 + i2;
#pragma unroll
        for (int j2 = 0; j2 < 4; ++j2) {
            int col = col0 + tx * 4 + j2;
            float v = acc[i2][j2] + bias[col];
            size_t idx = (size_t)row * N + col;
            if (mode == 1)      v = siluf_(v);
            else if (mode == 2) v = v * siluf_(other[idx]);
            else if (mode == 3) v = v * other[idx];
            C[idx] = v;
        }
    }
}

// ---------------- tiny GEMMs for ang/abs heads (N=8 each), fused activation*scale ----------
// a_out[n,h] = silu(x@w_ang+b_ang)[n,h] * scale[h]   (imag coefficient)
// r_out[n,h] = sigmoid(x@w_abs+b_abs)[n,h] * scale[h] (positive real coefficient)
__global__ __launch_bounds__(128) void angabs_kernel(
    const float* __restrict__ x,
    const float* __restrict__ w_ang, const float* __restrict__ b_ang,
    const float* __restrict__ w_abs, const float* __restrict__ b_abs,
    float* __restrict__ a_out, float* __restrict__ r_out)
{
    const int tid = threadIdx.x;
    const int rloc = tid >> 4;       // 0..7 (row within block)
    const int c = tid & 15;          // 0..15 : 0-7 -> ang head, 8-15 -> abs head
    const int n = blockIdx.x * 8 + rloc;
    const int h = c & 7;
    const float* w = (c < 8) ? w_ang : w_abs;
    const float* xr = x + (size_t)n * D_;
    float acc = 0.f;
    for (int k = 0; k < D_; ++k) acc = fmaf(xr[k], w[k * H_ + h], acc);
    acc += (c < 8) ? b_ang[h] : b_abs[h];
    const float scale = expf(-6.9077552789821368f * (h * (1.0f / 7.0f)));  // 0.001^(h/7)
    if (c < 8) a_out[(size_t)n * H_ + h] = siluf_(acc) * scale;
    else       r_out[(size_t)n * H_ + h] = sigmoidf_(acc) * scale;
}

// ---------------- inclusive scan over l for each (b,h): Si = cumsum(a), Sr = -cumsum(r) ----
__global__ __launch_bounds__(256) void scan_kernel(
    const float* __restrict__ a, const float* __restrict__ r,
    float* __restrict__ Si, float* __restrict__ Sr)
{
    const int bh = blockIdx.x;
    const int b = bh >> 3, h = bh & 7;
    const int tid = threadIdx.x;
    __shared__ float2 buf[2][256];

    float2 v[4];
    float2 run = make_float2(0.f, 0.f);
    const size_t base = ((size_t)b * L_ + tid * 4) * H_ + h;
#pragma unroll
    for (int j = 0; j < 4; ++j) {
        run.x += a[base + j * H_];
        run.y += r[base + j * H_];
        v[j] = run;
    }
    buf[0][tid] = run;
    __syncthreads();
    int src = 0;
    for (int off = 1; off < 256; off <<= 1) {
        float2 val = buf[src][tid];
        if (tid >= off) { float2 p = buf[src][tid - off]; val.x += p.x; val.y += p.y; }
        buf[src ^ 1][tid] = val;
        src ^= 1;
        __syncthreads();
    }
    float2 excl = make_float2(0.f, 0.f);
    if (tid > 0) excl = buf[src][tid - 1];
#pragma unroll
    for (int j = 0; j < 4; ++j) {
        Si[base + j * H_] = v[j].x + excl.x;
        Sr[base + j * H_] = -(v[j].y + excl.y);
    }
}

// ---------------- Zs[b,h,i] = sum_{m>h} z[b,m,h,i];  zdiag[b,h,i] = z[b,h,h,i] -------------
__global__ __launch_bounds__(256) void zs_kernel(
    const float* __restrict__ z, float* __restrict__ Zs, float* __restrict__ zdiag)
{
    const int bh = blockIdx.x;
    const int b = bh >> 3, h = bh & 7;
    const int tid = threadIdx.x;
    const int i = tid & 63;
    const int chunk = tid >> 6;  // 0..3
    float acc = 0.f;
    for (int m = h + 1 + chunk; m < L_; m += 4)
        acc += z[(((size_t)b * L_ + m) * H_ + h) * I_ + i];
    __shared__ float red[256];
    red[tid] = acc;
    __syncthreads();
    if (chunk == 0) {
        float s = red[i] + red[64 + i] + red[128 + i] + red[192 + i];
        Zs[(size_t)bh * I_ + i] = s;
        zdiag[(size_t)bh * I_ + i] = z[(((size_t)b * L_ + h) * H_ + h) * I_ + i];
    }
}

// ---------------- h = zdiag + e^Sr (cos(Si)(Zs+lc_r) - sin(Si) lc_i);  GroupNorm over I ----
__global__ __launch_bounds__(512) void hgn_kernel(
    const float* __restrict__ Sr, const float* __restrict__ Si,
    const float* __restrict__ Zs, const float* __restrict__ zdiag,
    const float* __restrict__ lc_r, const float* __restrict__ lc_i,
    const float* __restrict__ gn_w, const float* __restrict__ gn_b,
    float* __restrict__ h_norm)
{
    const int n = blockIdx.x;          // b*L + l
    const int b = n / L_;
    const int tid = threadIdx.x;       // 0..511
    const int h = tid >> 6, i = tid & 63;

    const float sr = Sr[(size_t)n * H_ + h];
    const float si = Si[(size_t)n * H_ + h];
    const float er = expf(sr);
    const float cs = cosf(si), sn = sinf(si);
    const size_t bhi = ((size_t)b * H_ + h) * I_ + i;
    const float cr = Zs[bhi] + lc_r[h * I_ + i];
    const float ci = lc_i[h * I_ + i];
    float hv = zdiag[bhi] + er * (cs * cr - sn * ci);

    // wave-level (64-lane) reduction: each wave == one head
    float sum = hv, sq = hv * hv;
#pragma unroll
    for (int o = 32; o > 0; o >>= 1) {
        sum += __shfl_xor(sum, o);
        sq  += __shfl_xor(sq, o);
    }
    const float mean = sum * (1.f / 64.f);
    const float var = sq * (1.f / 64.f) - mean * mean;
    const float inv = rsqrtf(var + 1e-5f);
    h_norm[(size_t)n * D_ + tid] = (hv - mean) * inv * gn_w[h] + gn_b[h];
}

extern "C" void kernel_launch(void* const* d_in, const int* in_sizes, int n_in,
                              void* d_out, int out_size, void* d_ws, size_t ws_size,
                              hipStream_t stream) {
    (void)n_in; (void)out_size; (void)ws_size;
    const float* x     = (const float*)d_in[0];
    const float* w_z   = (const float*)d_in[1];
    const float* b_z   = (const float*)d_in[2];
    const float* w_za  = (const float*)d_in[3];
    const float* b_za  = (const float*)d_in[4];
    const float* w_ang = (const float*)d_in[5];
    const float* b_ang = (const float*)d_in[6];
    const float* w_abs = (const float*)d_in[7];
    const float* b_abs = (const float*)d_in[8];
    const float* w_y   = (const float*)d_in[9];
    const float* b_y   = (const float*)d_in[10];
    const float* w_ya  = (const float*)d_in[11];
    const float* b_ya  = (const float*)d_in[12];
    const float* gn_w  = (const float*)d_in[13];
    const float* gn_b  = (const float*)d_in[14];
    const float* lc_r  = (const float*)d_in[15];
    const float* lc_i  = (const float*)d_in[16];
    float* y = (float*)d_out;

    const int BL = in_sizes[0] / D_;   // B*L = 2048
    const int B  = BL / L_;            // 2

    float* ws    = (float*)d_ws;
    float* t_za  = ws;                          // BL*D
    float* gate  = t_za  + (size_t)BL * D_;     // BL*D
    float* z     = gate  + (size_t)BL * D_;     // BL*D
    float* hnorm = z     + (size_t)BL * D_;     // BL*D
    float* a_arr = hnorm + (size_t)BL * D_;     // BL*H
    float* r_arr = a_arr + (size_t)BL * H_;     // BL*H
    float* Si    = r_arr + (size_t)BL * H_;     // BL*H
    float* Sr    = Si    + (size_t)BL * H_;     // BL*H
    float* Zs    = Sr    + (size_t)BL * H_;     // B*H*I
    float* zdiag = Zs    + (size_t)B * H_ * I_; // B*H*I

    dim3 gg(D_ / BN, BL / BM);   // (8, 32)

    // t_za = x@w_za + b_za
    gemm_f32<<<gg, 256, 0, stream>>>(x, w_za, b_za, t_za, nullptr, BL, D_, D_, 0);
    // gate = silu(x@w_ya + b_ya)
    gemm_f32<<<gg, 256, 0, stream>>>(x, w_ya, b_ya, gate, nullptr, BL, D_, D_, 1);
    // z = (x@w_z + b_z) * silu(t_za)
    gemm_f32<<<gg, 256, 0, stream>>>(x, w_z, b_z, z, t_za, BL, D_, D_, 2);
    // a,r per (n,h)
    angabs_kernel<<<BL / 8, 128, 0, stream>>>(x, w_ang, b_ang, w_abs, b_abs, a_arr, r_arr);
    // Si = cumsum(a), Sr = -cumsum(r) over l per (b,h)
    scan_kernel<<<B * H_, 256, 0, stream>>>(a_arr, r_arr, Si, Sr);
    // Zs, zdiag
    zs_kernel<<<B * H_, 256, 0, stream>>>(z, Zs, zdiag);
    // h + GroupNorm -> hnorm
    hgn_kernel<<<BL, 512, 0, stream>>>(Sr, Si, Zs, zdiag, lc_r, lc_i, gn_w, gn_b, hnorm);
    // y = (hnorm@w_y + b_y) * gate
    gemm_f32<<<gg, 256, 0, stream>>>(hnorm, w_y, b_y, y, gate, BL, D_, D_, 3);
}

// Round 2
// 60.279 us; speedup vs baseline: 3.9098x; 3.9098x over previous
//
#include <hip/hip_runtime.h>
#include <math.h>

#define D_ 512
#define H_ 8
#define I_ 64
#define L_ 1024

typedef __attribute__((ext_vector_type(8))) short short8;
typedef __attribute__((ext_vector_type(4))) float f32x4;

__device__ __forceinline__ float sigmoidf_(float x) { return 1.f / (1.f + expf(-x)); }
__device__ __forceinline__ float siluf_(float x) { return x / (1.f + expf(-x)); }

__device__ __forceinline__ unsigned short f2bf(float f) {
    unsigned u = __float_as_uint(f);
    u += 0x7fffu + ((u >> 16) & 1u);   // round-to-nearest-even
    return (unsigned short)(u >> 16);
}

// ---------- x (fp32) -> bf16, vectorized ----------
__global__ __launch_bounds__(256) void convert_x_kernel(
    const float* __restrict__ x, unsigned short* __restrict__ xb)
{
    int gid = blockIdx.x * 256 + threadIdx.x;
    float4 v = ((const float4*)x)[gid];
    ushort4 o = { f2bf(v.x), f2bf(v.y), f2bf(v.z), f2bf(v.w) };
    ((ushort4*)xb)[gid] = o;
}

// ---------- W[k][n] fp32 -> Wt[n][k] bf16 (4 matrices via blockIdx.z) ----------
__global__ __launch_bounds__(256) void transpose_w_kernel(
    const float* __restrict__ w0, const float* __restrict__ w1,
    const float* __restrict__ w2, const float* __restrict__ w3,
    unsigned short* __restrict__ t0, unsigned short* __restrict__ t1,
    unsigned short* __restrict__ t2, unsigned short* __restrict__ t3)
{
    const float* src = blockIdx.z == 0 ? w0 : blockIdx.z == 1 ? w1 : blockIdx.z == 2 ? w2 : w3;
    unsigned short* dst = blockIdx.z == 0 ? t0 : blockIdx.z == 1 ? t1 : blockIdx.z == 2 ? t2 : t3;
    __shared__ float t[64][65];
    const int k0 = blockIdx.y * 64, n0 = blockIdx.x * 64;
    const int tid = threadIdx.x;
#pragma unroll
    for (int i = 0; i < 16; ++i) {
        int idx = tid + i * 256;
        int rr = idx >> 6, cc = idx & 63;
        t[rr][cc] = src[(size_t)(k0 + rr) * 512 + n0 + cc];
    }
    __syncthreads();
#pragma unroll
    for (int i = 0; i < 16; ++i) {
        int idx = tid + i * 256;
        int rr = idx >> 6, cc = idx & 63;   // rr = n-local, cc = k-local
        dst[(size_t)(n0 + rr) * 512 + k0 + cc] = f2bf(t[cc][rr]);
    }
}

// ---------- fused z/za/ya GEMM (bf16 MFMA) with Zs/zdiag/gate epilogue ----------
// A = xb [M][512] bf16 row-major, W* = Wt [n][k] bf16.  Tile 64x64, BK=32, 4 waves 2x2.
__global__ __launch_bounds__(256) void gemm_fused3(
    const unsigned short* __restrict__ Axb,
    const unsigned short* __restrict__ Wz, const unsigned short* __restrict__ Wza,
    const unsigned short* __restrict__ Wya,
    const float* __restrict__ b_z, const float* __restrict__ b_za, const float* __restrict__ b_ya,
    float* __restrict__ gate, float* __restrict__ Zs, float* __restrict__ zdiag)
{
    __shared__ short As[64 * 32];
    __shared__ short Bs[3][64 * 32];
    __shared__ float red[64][8];
    const int tid = threadIdx.x;
    const int lane = tid & 63, w = tid >> 6;
    const int wm = w >> 1, wn = w & 1;
    const int bx = blockIdx.x;                 // == head h (BN=64=I, N=512)
    const int row0 = blockIdx.y * 64, col0 = bx * 64;

    const f32x4 zf = {0.f, 0.f, 0.f, 0.f};
    f32x4 accz[2][2], accza[2][2], accya[2][2];
#pragma unroll
    for (int a = 0; a < 2; ++a)
#pragma unroll
        for (int bq = 0; bq < 2; ++bq) { accz[a][bq] = zf; accza[a][bq] = zf; accya[a][bq] = zf; }

    const int sr = tid >> 2, sc = tid & 3;
    const int sld = sr * 64 + ((sc ^ ((sr >> 1) & 3)) << 4);   // swizzled LDS byte offset
    const size_t gA = (size_t)(row0 + sr) * 512 + sc * 8;
    const size_t gB = (size_t)(col0 + sr) * 512 + sc * 8;

    for (int k0 = 0; k0 < 512; k0 += 32) {
        *(int4*)((char*)As + sld)    = *(const int4*)(Axb + gA + k0);
        *(int4*)((char*)Bs[0] + sld) = *(const int4*)(Wz  + gB + k0);
        *(int4*)((char*)Bs[1] + sld) = *(const int4*)(Wza + gB + k0);
        *(int4*)((char*)Bs[2] + sld) = *(const int4*)(Wya + gB + k0);
        __syncthreads();
        short8 af[2], bz[2], bza[2], bya[2];
#pragma unroll
        for (int fi = 0; fi < 2; ++fi) {
            int rr = wm * 32 + fi * 16 + (lane & 15);
            int off = rr * 64 + ((((lane >> 4)) ^ ((rr >> 1) & 3)) << 4);
            af[fi] = *(const short8*)((const char*)As + off);
        }
#pragma unroll
        for (int fj = 0; fj < 2; ++fj) {
            int rr = wn * 32 + fj * 16 + (lane & 15);
            int off = rr * 64 + ((((lane >> 4)) ^ ((rr >> 1) & 3)) << 4);
            bz[fj]  = *(const short8*)((const char*)Bs[0] + off);
            bza[fj] = *(const short8*)((const char*)Bs[1] + off);
            bya[fj] = *(const short8*)((const char*)Bs[2] + off);
        }
#pragma unroll
        for (int fi = 0; fi < 2; ++fi)
#pragma unroll
            for (int fj = 0; fj < 2; ++fj) {
                accz[fi][fj]  = __builtin_amdgcn_mfma_f32_16x16x32_bf16(af[fi], bz[fj],  accz[fi][fj],  0, 0, 0);
                accza[fi][fj] = __builtin_amdgcn_mfma_f32_16x16x32_bf16(af[fi], bza[fj], accza[fi][fj], 0, 0, 0);
                accya[fi][fj] = __builtin_amdgcn_mfma_f32_16x16x32_bf16(af[fi], bya[fj], accya[fi][fj], 0, 0, 0);
            }
        __syncthreads();
    }

    const bool first = (row0 & (L_ - 1)) == 0;   // rows l in [0,64): contains l<=h and diag
    const int b8 = (row0 >> 10) * 8;
#pragma unroll
    for (int fj = 0; fj < 2; ++fj) {
        float lsum = 0.f;
        int lc = wn * 32 + fj * 16 + (lane & 15);
        int col = col0 + lc;
        float Bz = b_z[col], Bza = b_za[col], Bya = b_ya[col];
#pragma unroll
        for (int fi = 0; fi < 2; ++fi) {
#pragma unroll
            for (int q = 0; q < 4; ++q) {
                int lr = wm * 32 + fi * 16 + ((lane >> 4) << 2) + q;
                int row = row0 + lr;
                float pz = accz[fi][fj][q] + Bz;
                float pza = accza[fi][fj][q] + Bza;
                float v = pz * siluf_(pza);
                gate[(size_t)row * 512 + col] = siluf_(accya[fi][fj][q] + Bya);
                if (!first || lr > bx) lsum += v;
                if (first && lr == bx) zdiag[(b8 + bx) * 64 + lc] = v;
            }
        }
        red[lc][wm * 4 + (lane >> 4)] = lsum;
    }
    __syncthreads();
    if (tid < 64) {
        float s = 0.f;
#pragma unroll
        for (int j = 0; j < 8; ++j) s += red[tid][j];
        atomicAdd(&Zs[(b8 + bx) * 64 + tid], s);
    }
}

// ---------- final GEMM: y = (hnorm @ w_y + b_y) * gate ----------
__global__ __launch_bounds__(256) void gemm_y_kernel(
    const unsigned short* __restrict__ Ah, const unsigned short* __restrict__ Wy,
    const float* __restrict__ b_y, const float* __restrict__ gate, float* __restrict__ y)
{
    __shared__ short As[64 * 32];
    __shared__ short Bsy[64 * 32];
    const int tid = threadIdx.x;
    const int lane = tid & 63, w = tid >> 6;
    const int wm = w >> 1, wn = w & 1;
    const int row0 = blockIdx.y * 64, col0 = blockIdx.x * 64;

    const f32x4 zf = {0.f, 0.f, 0.f, 0.f};
    f32x4 acc[2][2];
#pragma unroll
    for (int a = 0; a < 2; ++a)
#pragma unroll
        for (int bq = 0; bq < 2; ++bq) acc[a][bq] = zf;

    const int sr = tid >> 2, sc = tid & 3;
    const int sld = sr * 64 + ((sc ^ ((sr >> 1) & 3)) << 4);
    const size_t gA = (size_t)(row0 + sr) * 512 + sc * 8;
    const size_t gB = (size_t)(col0 + sr) * 512 + sc * 8;

    for (int k0 = 0; k0 < 512; k0 += 32) {
        *(int4*)((char*)As + sld)  = *(const int4*)(Ah + gA + k0);
        *(int4*)((char*)Bsy + sld) = *(const int4*)(Wy + gB + k0);
        __syncthreads();
        short8 af[2], bf[2];
#pragma unroll
        for (int fi = 0; fi < 2; ++fi) {
            int rr = wm * 32 + fi * 16 + (lane & 15);
            int off = rr * 64 + ((((lane >> 4)) ^ ((rr >> 1) & 3)) << 4);
            af[fi] = *(const short8*)((const char*)As + off);
        }
#pragma unroll
        for (int fj = 0; fj < 2; ++fj) {
            int rr = wn * 32 + fj * 16 + (lane & 15);
            int off = rr * 64 + ((((lane >> 4)) ^ ((rr >> 1) & 3)) << 4);
            bf[fj] = *(const short8*)((const char*)Bsy + off);
        }
#pragma unroll
        for (int fi = 0; fi < 2; ++fi)
#pragma unroll
            for (int fj = 0; fj < 2; ++fj)
                acc[fi][fj] = __builtin_amdgcn_mfma_f32_16x16x32_bf16(af[fi], bf[fj], acc[fi][fj], 0, 0, 0);
        __syncthreads();
    }

#pragma unroll
    for (int fj = 0; fj < 2; ++fj) {
        int col = col0 + wn * 32 + fj * 16 + (lane & 15);
        float By = b_y[col];
#pragma unroll
        for (int fi = 0; fi < 2; ++fi)
#pragma unroll
            for (int q = 0; q < 4; ++q) {
                int row = row0 + wm * 32 + fi * 16 + ((lane >> 4) << 2) + q;
                size_t idx = (size_t)row * 512 + col;
                y[idx] = (acc[fi][fj][q] + By) * gate[idx];
            }
    }
}

// ---------- ang/abs heads (fp32 for precision; feeds the cumulative sums) ----------
__global__ __launch_bounds__(256) void angabs_kernel(
    const float* __restrict__ x,
    const float* __restrict__ w_ang, const float* __restrict__ b_ang,
    const float* __restrict__ w_abs, const float* __restrict__ b_abs,
    float* __restrict__ a_out, float* __restrict__ r_out)
{
    const int tid = threadIdx.x;
    const int s = tid & 3, c = (tid >> 2) & 15, r = tid >> 6;
    const int n = blockIdx.x * 4 + r;
    const int h = c & 7;
    const float* wp = (c < 8) ? w_ang : w_abs;
    const float* xr = x + (size_t)n * D_;
    float acc = 0.f;
#pragma unroll 4
    for (int i = 0; i < 128; ++i) {
        int k = i * 4 + s;
        acc = fmaf(xr[k], wp[k * H_ + h], acc);
    }
    acc += __shfl_xor(acc, 1);
    acc += __shfl_xor(acc, 2);
    if (s == 0) {
        const float scale = expf(-6.9077552789821368f * (h * (1.0f / 7.0f)));  // 0.001^(h/7)
        if (c < 8) { float p = acc + b_ang[h]; a_out[(size_t)n * H_ + h] = siluf_(p) * scale; }
        else       { float p = acc + b_abs[h]; r_out[(size_t)n * H_ + h] = sigmoidf_(p) * scale; }
    }
}

// ---------- inclusive scan over l per (b,h) ----------
__global__ __launch_bounds__(256) void scan_kernel(
    const float* __restrict__ a, const float* __restrict__ r,
    float* __restrict__ Si, float* __restrict__ Sr)
{
    const int bh = blockIdx.x;
    const int b = bh >> 3, h = bh & 7;
    const int tid = threadIdx.x;
    __shared__ float2 buf[2][256];

    float2 v[4];
    float2 run = make_float2(0.f, 0.f);
    const size_t base = ((size_t)b * L_ + tid * 4) * H_ + h;
#pragma unroll
    for (int j = 0; j < 4; ++j) {
        run.x += a[base + j * H_];
        run.y += r[base + j * H_];
        v[j] = run;
    }
    buf[0][tid] = run;
    __syncthreads();
    int src = 0;
    for (int off = 1; off < 256; off <<= 1) {
        float2 val = buf[src][tid];
        if (tid >= off) { float2 p = buf[src][tid - off]; val.x += p.x; val.y += p.y; }
        buf[src ^ 1][tid] = val;
        src ^= 1;
        __syncthreads();
    }
    float2 excl = make_float2(0.f, 0.f);
    if (tid > 0) excl = buf[src][tid - 1];
#pragma unroll
    for (int j = 0; j < 4; ++j) {
        Si[base + j * H_] = v[j].x + excl.x;
        Sr[base + j * H_] = -(v[j].y + excl.y);
    }
}

// ---------- h = zdiag + e^Sr (cos(Si)(Zs+lc_r) - sin(Si) lc_i); GroupNorm; bf16 out ----------
__global__ __launch_bounds__(512) void hgn_kernel(
    const float* __restrict__ Sr, const float* __restrict__ Si,
    const float* __restrict__ Zs, const float* __restrict__ zdiag,
    const float* __restrict__ lc_r, const float* __restrict__ lc_i,
    const float* __restrict__ gn_w, const float* __restrict__ gn_b,
    unsigned short* __restrict__ h_norm)
{
    const int n = blockIdx.x;          // b*L + l
    const int b = n / L_;
    const int tid = threadIdx.x;       // 0..511
    const int h = tid >> 6, i = tid & 63;

    const float sr = Sr[(size_t)n * H_ + h];
    const float si = Si[(size_t)n * H_ + h];
    const float er = expf(sr);
    const float cs = cosf(si), sn = sinf(si);
    const size_t bhi = ((size_t)b * H_ + h) * I_ + i;
    const float cr = Zs[bhi] + lc_r[h * I_ + i];
    const float ci = lc_i[h * I_ + i];
    float hv = zdiag[bhi] + er * (cs * cr - sn * ci);

    float sum = hv, sq = hv * hv;
#pragma unroll
    for (int o = 32; o > 0; o >>= 1) {
        sum += __shfl_xor(sum, o);
        sq  += __shfl_xor(sq, o);
    }
    const float mean = sum * (1.f / 64.f);
    const float var = sq * (1.f / 64.f) - mean * mean;
    const float inv = rsqrtf(var + 1e-5f);
    h_norm[(size_t)n * D_ + tid] = f2bf((hv - mean) * inv * gn_w[h] + gn_b[h]);
}

extern "C" void kernel_launch(void* const* d_in, const int* in_sizes, int n_in,
                              void* d_out, int out_size, void* d_ws, size_t ws_size,
                              hipStream_t stream) {
    (void)n_in; (void)out_size; (void)ws_size;
    const float* x     = (const float*)d_in[0];
    const float* w_z   = (const float*)d_in[1];
    const float* b_z   = (const float*)d_in[2];
    const float* w_za  = (const float*)d_in[3];
    const float* b_za  = (const float*)d_in[4];
    const float* w_ang = (const float*)d_in[5];
    const float* b_ang = (const float*)d_in[6];
    const float* w_abs = (const float*)d_in[7];
    const float* b_abs = (const float*)d_in[8];
    const float* w_y   = (const float*)d_in[9];
    const float* b_y   = (const float*)d_in[10];
    const float* w_ya  = (const float*)d_in[11];
    const float* b_ya  = (const float*)d_in[12];
    const float* gn_w  = (const float*)d_in[13];
    const float* gn_b  = (const float*)d_in[14];
    const float* lc_r  = (const float*)d_in[15];
    const float* lc_i  = (const float*)d_in[16];
    float* y = (float*)d_out;

    const int BL = in_sizes[0] / D_;   // 2048
    const int B  = BL / L_;            // 2

    unsigned short* xb   = (unsigned short*)d_ws;            // BL*512
    unsigned short* wtz  = xb   + (size_t)BL * 512;          // 512*512 each
    unsigned short* wtza = wtz  + 512 * 512;
    unsigned short* wtya = wtza + 512 * 512;
    unsigned short* wty  = wtya + 512 * 512;
    unsigned short* hnb  = wty  + 512 * 512;                 // BL*512
    float* gate  = (float*)(hnb + (size_t)BL * 512);         // BL*512 f32
    float* a_arr = gate  + (size_t)BL * 512;                 // BL*H
    float* r_arr = a_arr + (size_t)BL * H_;
    float* Si    = r_arr + (size_t)BL * H_;
    float* Sr    = Si    + (size_t)BL * H_;
    float* Zs    = Sr    + (size_t)BL * H_;                  // B*H*I
    float* zdiag = Zs    + (size_t)B * H_ * I_;              // B*H*I

    convert_x_kernel<<<(BL * 512) / 1024, 256, 0, stream>>>(x, xb);
    transpose_w_kernel<<<dim3(8, 8, 4), 256, 0, stream>>>(w_z, w_za, w_ya, w_y, wtz, wtza, wtya, wty);
    hipMemsetAsync(Zs, 0, (size_t)B * H_ * I_ * sizeof(float), stream);
    gemm_fused3<<<dim3(8, BL / 64), 256, 0, stream>>>(xb, wtz, wtza, wtya, b_z, b_za, b_ya,
                                                      gate, Zs, zdiag);
    angabs_kernel<<<BL / 4, 256, 0, stream>>>(x, w_ang, b_ang, w_abs, b_abs, a_arr, r_arr);
    scan_kernel<<<B * H_, 256, 0, stream>>>(a_arr, r_arr, Si, Sr);
    hgn_kernel<<<BL, 512, 0, stream>>>(Sr, Si, Zs, zdiag, lc_r, lc_i, gn_w, gn_b, hnb);
    gemm_y_kernel<<<dim3(8, BL / 64), 256, 0, stream>>>(hnb, wty, b_y, gate, y);
}

// Round 3
// 59.474 us; speedup vs baseline: 3.9628x; 1.0135x over previous
//
#include <hip/hip_runtime.h>
#include <math.h>

#define D_ 512
#define H_ 8
#define I_ 64
#define L_ 1024

typedef __attribute__((ext_vector_type(8))) short short8;
typedef __attribute__((ext_vector_type(4))) float f32x4;

__device__ __forceinline__ float sigmoidf_(float x) { return 1.f / (1.f + expf(-x)); }
__device__ __forceinline__ float siluf_(float x) { return x / (1.f + expf(-x)); }

__device__ __forceinline__ unsigned short f2bf(float f) {
    unsigned u = __float_as_uint(f);
    u += 0x7fffu + ((u >> 16) & 1u);   // round-to-nearest-even
    return (unsigned short)(u >> 16);
}
__device__ __forceinline__ float bf2f(unsigned short v) {
    return __uint_as_float((unsigned)v << 16);
}

// ---------- prep: x fp32->bf16 (blocks [0,nconv)) + 4x W[k][n]->Wt[n][k] bf16 ----------
__global__ __launch_bounds__(256) void prep_kernel(
    const float* __restrict__ x, unsigned short* __restrict__ xb, int nconv,
    const float* __restrict__ w0, const float* __restrict__ w1,
    const float* __restrict__ w2, const float* __restrict__ w3,
    unsigned short* __restrict__ t0, unsigned short* __restrict__ t1,
    unsigned short* __restrict__ t2, unsigned short* __restrict__ t3)
{
    __shared__ float sm[64][65];
    const int tid = threadIdx.x;
    if ((int)blockIdx.x < nconv) {
        int gid = blockIdx.x * 256 + tid;
        float4 v = ((const float4*)x)[gid];
        ushort4 o = { f2bf(v.x), f2bf(v.y), f2bf(v.z), f2bf(v.w) };
        ((ushort4*)xb)[gid] = o;
        return;
    }
    int t = blockIdx.x - nconv;          // 0..255
    int zsel = t >> 6, tile = t & 63;
    const float* src = zsel == 0 ? w0 : zsel == 1 ? w1 : zsel == 2 ? w2 : w3;
    unsigned short* dst = zsel == 0 ? t0 : zsel == 1 ? t1 : zsel == 2 ? t2 : t3;
    const int k0 = (tile >> 3) * 64, n0 = (tile & 7) * 64;
#pragma unroll
    for (int i = 0; i < 16; ++i) {
        int idx = tid + i * 256;
        int rr = idx >> 6, cc = idx & 63;
        sm[rr][cc] = src[(size_t)(k0 + rr) * 512 + n0 + cc];
    }
    __syncthreads();
#pragma unroll
    for (int i = 0; i < 16; ++i) {
        int idx = tid + i * 256;
        int rr = idx >> 6, cc = idx & 63;   // rr = n-local, cc = k-local
        dst[(size_t)(n0 + rr) * 512 + k0 + cc] = f2bf(sm[cc][rr]);
    }
}

// ---------- fused z/za/ya GEMM (bf16 MFMA): gate(bf16), zdiag, Zs_part epilogue ----------
__global__ __launch_bounds__(256) void gemm_fused3(
    const unsigned short* __restrict__ Axb,
    const unsigned short* __restrict__ Wz, const unsigned short* __restrict__ Wza,
    const unsigned short* __restrict__ Wya,
    const float* __restrict__ b_z, const float* __restrict__ b_za, const float* __restrict__ b_ya,
    unsigned short* __restrict__ gateb, float* __restrict__ Zs_part, float* __restrict__ zdiag)
{
    __shared__ short As[64 * 32];
    __shared__ short Bs[3][64 * 32];
    __shared__ float red[64][8];
    const int tid = threadIdx.x;
    const int lane = tid & 63, w = tid >> 6;
    const int wm = w >> 1, wn = w & 1;
    const int bx = blockIdx.x;                 // == head h (BN=64=I, N=512)
    const int row0 = blockIdx.y * 64, col0 = bx * 64;

    const f32x4 zf = {0.f, 0.f, 0.f, 0.f};
    f32x4 accz[2][2], accza[2][2], accya[2][2];
#pragma unroll
    for (int a = 0; a < 2; ++a)
#pragma unroll
        for (int bq = 0; bq < 2; ++bq) { accz[a][bq] = zf; accza[a][bq] = zf; accya[a][bq] = zf; }

    const int sr = tid >> 2, sc = tid & 3;
    const int sld = sr * 64 + ((sc ^ ((sr >> 1) & 3)) << 4);   // swizzled LDS byte offset
    const size_t gA = (size_t)(row0 + sr) * 512 + sc * 8;
    const size_t gB = (size_t)(col0 + sr) * 512 + sc * 8;

    for (int k0 = 0; k0 < 512; k0 += 32) {
        *(int4*)((char*)As + sld)    = *(const int4*)(Axb + gA + k0);
        *(int4*)((char*)Bs[0] + sld) = *(const int4*)(Wz  + gB + k0);
        *(int4*)((char*)Bs[1] + sld) = *(const int4*)(Wza + gB + k0);
        *(int4*)((char*)Bs[2] + sld) = *(const int4*)(Wya + gB + k0);
        __syncthreads();
        short8 af[2], bz[2], bza[2], bya[2];
#pragma unroll
        for (int fi = 0; fi < 2; ++fi) {
            int rr = wm * 32 + fi * 16 + (lane & 15);
            int off = rr * 64 + ((((lane >> 4)) ^ ((rr >> 1) & 3)) << 4);
            af[fi] = *(const short8*)((const char*)As + off);
        }
#pragma unroll
        for (int fj = 0; fj < 2; ++fj) {
            int rr = wn * 32 + fj * 16 + (lane & 15);
            int off = rr * 64 + ((((lane >> 4)) ^ ((rr >> 1) & 3)) << 4);
            bz[fj]  = *(const short8*)((const char*)Bs[0] + off);
            bza[fj] = *(const short8*)((const char*)Bs[1] + off);
            bya[fj] = *(const short8*)((const char*)Bs[2] + off);
        }
#pragma unroll
        for (int fi = 0; fi < 2; ++fi)
#pragma unroll
            for (int fj = 0; fj < 2; ++fj) {
                accz[fi][fj]  = __builtin_amdgcn_mfma_f32_16x16x32_bf16(af[fi], bz[fj],  accz[fi][fj],  0, 0, 0);
                accza[fi][fj] = __builtin_amdgcn_mfma_f32_16x16x32_bf16(af[fi], bza[fj], accza[fi][fj], 0, 0, 0);
                accya[fi][fj] = __builtin_amdgcn_mfma_f32_16x16x32_bf16(af[fi], bya[fj], accya[fi][fj], 0, 0, 0);
            }
        __syncthreads();
    }

    const bool first = (row0 & (L_ - 1)) == 0;   // rows l in [0,64): contains l<=h and diag
    const int b8 = (row0 >> 10) * 8;
#pragma unroll
    for (int fj = 0; fj < 2; ++fj) {
        float lsum = 0.f;
        int lc = wn * 32 + fj * 16 + (lane & 15);
        int col = col0 + lc;
        float Bz = b_z[col], Bza = b_za[col], Bya = b_ya[col];
#pragma unroll
        for (int fi = 0; fi < 2; ++fi) {
#pragma unroll
            for (int q = 0; q < 4; ++q) {
                int lr = wm * 32 + fi * 16 + ((lane >> 4) << 2) + q;
                int row = row0 + lr;
                float pz = accz[fi][fj][q] + Bz;
                float pza = accza[fi][fj][q] + Bza;
                float v = pz * siluf_(pza);
                gateb[(size_t)row * 512 + col] = f2bf(siluf_(accya[fi][fj][q] + Bya));
                if (!first || lr > bx) lsum += v;
                if (first && lr == bx) zdiag[(b8 + bx) * 64 + lc] = v;
            }
        }
        red[lc][wm * 4 + (lane >> 4)] = lsum;
    }
    __syncthreads();
    if (tid < 64) {
        float s = 0.f;
#pragma unroll
        for (int j = 0; j < 8; ++j) s += red[tid][j];
        Zs_part[((size_t)blockIdx.y * 8 + bx) * 64 + tid] = s;   // race-free partials
    }
}

// ---------- final GEMM: y = (hnorm @ w_y + b_y) * gate ----------
__global__ __launch_bounds__(256) void gemm_y_kernel(
    const unsigned short* __restrict__ Ah, const unsigned short* __restrict__ Wy,
    const float* __restrict__ b_y, const unsigned short* __restrict__ gateb,
    float* __restrict__ y)
{
    __shared__ short As[64 * 32];
    __shared__ short Bsy[64 * 32];
    const int tid = threadIdx.x;
    const int lane = tid & 63, w = tid >> 6;
    const int wm = w >> 1, wn = w & 1;
    const int row0 = blockIdx.y * 64, col0 = blockIdx.x * 64;

    const f32x4 zf = {0.f, 0.f, 0.f, 0.f};
    f32x4 acc[2][2];
#pragma unroll
    for (int a = 0; a < 2; ++a)
#pragma unroll
        for (int bq = 0; bq < 2; ++bq) acc[a][bq] = zf;

    const int sr = tid >> 2, sc = tid & 3;
    const int sld = sr * 64 + ((sc ^ ((sr >> 1) & 3)) << 4);
    const size_t gA = (size_t)(row0 + sr) * 512 + sc * 8;
    const size_t gB = (size_t)(col0 + sr) * 512 + sc * 8;

    for (int k0 = 0; k0 < 512; k0 += 32) {
        *(int4*)((char*)As + sld)  = *(const int4*)(Ah + gA + k0);
        *(int4*)((char*)Bsy + sld) = *(const int4*)(Wy + gB + k0);
        __syncthreads();
        short8 af[2], bf[2];
#pragma unroll
        for (int fi = 0; fi < 2; ++fi) {
            int rr = wm * 32 + fi * 16 + (lane & 15);
            int off = rr * 64 + ((((lane >> 4)) ^ ((rr >> 1) & 3)) << 4);
            af[fi] = *(const short8*)((const char*)As + off);
        }
#pragma unroll
        for (int fj = 0; fj < 2; ++fj) {
            int rr = wn * 32 + fj * 16 + (lane & 15);
            int off = rr * 64 + ((((lane >> 4)) ^ ((rr >> 1) & 3)) << 4);
            bf[fj] = *(const short8*)((const char*)Bsy + off);
        }
#pragma unroll
        for (int fi = 0; fi < 2; ++fi)
#pragma unroll
            for (int fj = 0; fj < 2; ++fj)
                acc[fi][fj] = __builtin_amdgcn_mfma_f32_16x16x32_bf16(af[fi], bf[fj], acc[fi][fj], 0, 0, 0);
        __syncthreads();
    }

#pragma unroll
    for (int fj = 0; fj < 2; ++fj) {
        int col = col0 + wn * 32 + fj * 16 + (lane & 15);
        float By = b_y[col];
#pragma unroll
        for (int fi = 0; fi < 2; ++fi)
#pragma unroll
            for (int q = 0; q < 4; ++q) {
                int row = row0 + wm * 32 + fi * 16 + ((lane >> 4) << 2) + q;
                size_t idx = (size_t)row * 512 + col;
                y[idx] = (acc[fi][fj][q] + By) * bf2f(gateb[idx]);
            }
    }
}

// ---------- ang/abs heads (fp32 for precision; feeds the cumulative sums) ----------
__global__ __launch_bounds__(256) void angabs_kernel(
    const float* __restrict__ x,
    const float* __restrict__ w_ang, const float* __restrict__ b_ang,
    const float* __restrict__ w_abs, const float* __restrict__ b_abs,
    float* __restrict__ a_out, float* __restrict__ r_out)
{
    const int tid = threadIdx.x;
    const int s = tid & 3, c = (tid >> 2) & 15, r = tid >> 6;
    const int n = blockIdx.x * 4 + r;
    const int h = c & 7;
    const float* wp = (c < 8) ? w_ang : w_abs;
    const float* xr = x + (size_t)n * D_;
    float acc = 0.f;
#pragma unroll 4
    for (int i = 0; i < 128; ++i) {
        int k = i * 4 + s;
        acc = fmaf(xr[k], wp[k * H_ + h], acc);
    }
    acc += __shfl_xor(acc, 1);
    acc += __shfl_xor(acc, 2);
    if (s == 0) {
        const float scale = expf(-6.9077552789821368f * (h * (1.0f / 7.0f)));  // 0.001^(h/7)
        if (c < 8) { float p = acc + b_ang[h]; a_out[(size_t)n * H_ + h] = siluf_(p) * scale; }
        else       { float p = acc + b_abs[h]; r_out[(size_t)n * H_ + h] = sigmoidf_(p) * scale; }
    }
}

// ---------- inclusive scan over l per (b,h) + reduce Zs partials ----------
__global__ __launch_bounds__(256) void scan_kernel(
    const float* __restrict__ a, const float* __restrict__ r,
    float* __restrict__ Si, float* __restrict__ Sr,
    const float* __restrict__ Zs_part, float* __restrict__ Zs)
{
    const int bh = blockIdx.x;
    const int b = bh >> 3, h = bh & 7;
    const int tid = threadIdx.x;
    __shared__ float2 buf[2][256];
    __shared__ float zred[4][64];

    // ---- Zs[bh][i] = sum over 16 rowblocks of Zs_part[(b*16+rb)*8+h][i] ----
    {
        const int i = tid & 63, rq = tid >> 6;       // rq in 0..3
        float s = 0.f;
#pragma unroll
        for (int j = 0; j < 4; ++j) {
            int rb = rq * 4 + j;
            s += Zs_part[(((size_t)b * 16 + rb) * 8 + h) * 64 + i];
        }
        zred[rq][i] = s;
    }

    float2 v[4];
    float2 run = make_float2(0.f, 0.f);
    const size_t base = ((size_t)b * L_ + tid * 4) * H_ + h;
#pragma unroll
    for (int j = 0; j < 4; ++j) {
        run.x += a[base + j * H_];
        run.y += r[base + j * H_];
        v[j] = run;
    }
    buf[0][tid] = run;
    __syncthreads();
    if (tid < 64) Zs[(size_t)bh * 64 + tid] = zred[0][tid] + zred[1][tid] + zred[2][tid] + zred[3][tid];
    int src = 0;
    for (int off = 1; off < 256; off <<= 1) {
        float2 val = buf[src][tid];
        if (tid >= off) { float2 p = buf[src][tid - off]; val.x += p.x; val.y += p.y; }
        buf[src ^ 1][tid] = val;
        src ^= 1;
        __syncthreads();
    }
    float2 excl = make_float2(0.f, 0.f);
    if (tid > 0) excl = buf[src][tid - 1];
#pragma unroll
    for (int j = 0; j < 4; ++j) {
        Si[base + j * H_] = v[j].x + excl.x;
        Sr[base + j * H_] = -(v[j].y + excl.y);
    }
}

// ---------- h = zdiag + e^Sr (cos(Si)(Zs+lc_r) - sin(Si) lc_i); GroupNorm; bf16 out ----------
__global__ __launch_bounds__(512) void hgn_kernel(
    const float* __restrict__ Sr, const float* __restrict__ Si,
    const float* __restrict__ Zs, const float* __restrict__ zdiag,
    const float* __restrict__ lc_r, const float* __restrict__ lc_i,
    const float* __restrict__ gn_w, const float* __restrict__ gn_b,
    unsigned short* __restrict__ h_norm)
{
    const int n = blockIdx.x;          // b*L + l
    const int b = n / L_;
    const int tid = threadIdx.x;       // 0..511
    const int h = tid >> 6, i = tid & 63;

    const float sr = Sr[(size_t)n * H_ + h];
    const float si = Si[(size_t)n * H_ + h];
    const float er = expf(sr);
    const float cs = cosf(si), sn = sinf(si);
    const size_t bhi = ((size_t)b * H_ + h) * I_ + i;
    const float cr = Zs[bhi] + lc_r[h * I_ + i];
    const float ci = lc_i[h * I_ + i];
    float hv = zdiag[bhi] + er * (cs * cr - sn * ci);

    float sum = hv, sq = hv * hv;
#pragma unroll
    for (int o = 32; o > 0; o >>= 1) {
        sum += __shfl_xor(sum, o);
        sq  += __shfl_xor(sq, o);
    }
    const float mean = sum * (1.f / 64.f);
    const float var = sq * (1.f / 64.f) - mean * mean;
    const float inv = rsqrtf(var + 1e-5f);
    h_norm[(size_t)n * D_ + tid] = f2bf((hv - mean) * inv * gn_w[h] + gn_b[h]);
}

extern "C" void kernel_launch(void* const* d_in, const int* in_sizes, int n_in,
                              void* d_out, int out_size, void* d_ws, size_t ws_size,
                              hipStream_t stream) {
    (void)n_in; (void)out_size; (void)ws_size;
    const float* x     = (const float*)d_in[0];
    const float* w_z   = (const float*)d_in[1];
    const float* b_z   = (const float*)d_in[2];
    const float* w_za  = (const float*)d_in[3];
    const float* b_za  = (const float*)d_in[4];
    const float* w_ang = (const float*)d_in[5];
    const float* b_ang = (const float*)d_in[6];
    const float* w_abs = (const float*)d_in[7];
    const float* b_abs = (const float*)d_in[8];
    const float* w_y   = (const float*)d_in[9];
    const float* b_y   = (const float*)d_in[10];
    const float* w_ya  = (const float*)d_in[11];
    const float* b_ya  = (const float*)d_in[12];
    const float* gn_w  = (const float*)d_in[13];
    const float* gn_b  = (const float*)d_in[14];
    const float* lc_r  = (const float*)d_in[15];
    const float* lc_i  = (const float*)d_in[16];
    float* y = (float*)d_out;

    const int BL = in_sizes[0] / D_;   // 2048
    const int B  = BL / L_;            // 2

    unsigned short* xb   = (unsigned short*)d_ws;            // BL*512
    unsigned short* wtz  = xb   + (size_t)BL * 512;          // 512*512 each
    unsigned short* wtza = wtz  + 512 * 512;
    unsigned short* wtya = wtza + 512 * 512;
    unsigned short* wty  = wtya + 512 * 512;
    unsigned short* hnb  = wty  + 512 * 512;                 // BL*512
    unsigned short* gateb= hnb  + (size_t)BL * 512;          // BL*512
    float* a_arr = (float*)(gateb + (size_t)BL * 512);       // BL*H
    float* r_arr = a_arr + (size_t)BL * H_;
    float* Si    = r_arr + (size_t)BL * H_;
    float* Sr    = Si    + (size_t)BL * H_;
    float* Zs    = Sr    + (size_t)BL * H_;                  // B*H*I
    float* zdiag = Zs    + (size_t)B * H_ * I_;              // B*H*I
    float* Zs_part = zdiag + (size_t)B * H_ * I_;            // (BL/64)*H*I

    const int nconv = (BL * 512) / 1024;
    prep_kernel<<<nconv + 256, 256, 0, stream>>>(x, xb, nconv,
                                                 w_z, w_za, w_ya, w_y, wtz, wtza, wtya, wty);
    angabs_kernel<<<BL / 4, 256, 0, stream>>>(x, w_ang, b_ang, w_abs, b_abs, a_arr, r_arr);
    gemm_fused3<<<dim3(8, BL / 64), 256, 0, stream>>>(xb, wtz, wtza, wtya, b_z, b_za, b_ya,
                                                      gateb, Zs_part, zdiag);
    scan_kernel<<<B * H_, 256, 0, stream>>>(a_arr, r_arr, Si, Sr, Zs_part, Zs);
    hgn_kernel<<<BL, 512, 0, stream>>>(Sr, Si, Zs, zdiag, lc_r, lc_i, gn_w, gn_b, hnb);
    gemm_y_kernel<<<dim3(8, BL / 64), 256, 0, stream>>>(hnb, wty, b_y, gateb, y);
}

// Round 4
// 47.238 us; speedup vs baseline: 4.9892x; 1.2590x over previous
//
#include <hip/hip_runtime.h>
#include <math.h>

#define D_ 512
#define H_ 8
#define I_ 64
#define L_ 1024

typedef __attribute__((ext_vector_type(8))) short short8;
typedef __attribute__((ext_vector_type(4))) float f32x4;

__device__ __forceinline__ float sigmoidf_(float x) { return 1.f / (1.f + expf(-x)); }
__device__ __forceinline__ float siluf_(float x) { return x / (1.f + expf(-x)); }

__device__ __forceinline__ unsigned short f2bf(float f) {
    unsigned u = __float_as_uint(f);
    u += 0x7fffu + ((u >> 16) & 1u);   // round-to-nearest-even
    return (unsigned short)(u >> 16);
}
__device__ __forceinline__ float bf2f(unsigned short v) {
    return __uint_as_float((unsigned)v << 16);
}

// ================= K1: x->bf16 conv + 4x W transpose + angabs heads =================
__global__ __launch_bounds__(256) void k1_prep(
    const float* __restrict__ x, unsigned short* __restrict__ xb, int nconv,
    const float* __restrict__ w0, const float* __restrict__ w1,
    const float* __restrict__ w2, const float* __restrict__ w3,
    unsigned short* __restrict__ t0, unsigned short* __restrict__ t1,
    unsigned short* __restrict__ t2, unsigned short* __restrict__ t3,
    const float* __restrict__ w_ang, const float* __restrict__ b_ang,
    const float* __restrict__ w_abs, const float* __restrict__ b_abs,
    float* __restrict__ a_out, float* __restrict__ r_out)
{
    __shared__ float sm[64][65];
    const int tid = threadIdx.x;
    const int bid = blockIdx.x;
    if (bid < nconv) {
        // ---- fp32 -> bf16 conversion, 1024 floats/block ----
        int gid = bid * 256 + tid;
        float4 v = ((const float4*)x)[gid];
        ushort4 o = { f2bf(v.x), f2bf(v.y), f2bf(v.z), f2bf(v.w) };
        ((ushort4*)xb)[gid] = o;
        return;
    }
    if (bid < nconv + 256) {
        // ---- W[k][n] -> Wt[n][k] bf16 ----
        int t = bid - nconv;
        int zsel = t >> 6, tile = t & 63;
        const float* src = zsel == 0 ? w0 : zsel == 1 ? w1 : zsel == 2 ? w2 : w3;
        unsigned short* dst = zsel == 0 ? t0 : zsel == 1 ? t1 : zsel == 2 ? t2 : t3;
        const int k0 = (tile >> 3) * 64, n0 = (tile & 7) * 64;
#pragma unroll
        for (int i = 0; i < 16; ++i) {
            int idx = tid + i * 256;
            int rr = idx >> 6, cc = idx & 63;
            sm[rr][cc] = src[(size_t)(k0 + rr) * 512 + n0 + cc];
        }
        __syncthreads();
#pragma unroll
        for (int i = 0; i < 16; ++i) {
            int idx = tid + i * 256;
            int rr = idx >> 6, cc = idx & 63;   // rr = n-local, cc = k-local
            dst[(size_t)(n0 + rr) * 512 + k0 + cc] = f2bf(sm[cc][rr]);
        }
        return;
    }
    // ---- ang/abs heads, fp32 (feeds cumulative sums), 4 rows/block ----
    {
        int t = bid - nconv - 256;
        const int s = tid & 3, c = (tid >> 2) & 15, r = tid >> 6;
        const int n = t * 4 + r;
        const int h = c & 7;
        const float* wp = (c < 8) ? w_ang : w_abs;
        const float* xr = x + (size_t)n * D_;
        float acc = 0.f;
#pragma unroll 4
        for (int i = 0; i < 128; ++i) {
            int k = i * 4 + s;
            acc = fmaf(xr[k], wp[k * H_ + h], acc);
        }
        acc += __shfl_xor(acc, 1);
        acc += __shfl_xor(acc, 2);
        if (s == 0) {
            const float scale = expf(-6.9077552789821368f * (h * (1.0f / 7.0f)));  // 0.001^(h/7)
            if (c < 8) { float p = acc + b_ang[h]; a_out[(size_t)n * H_ + h] = siluf_(p) * scale; }
            else       { float p = acc + b_abs[h]; r_out[(size_t)n * H_ + h] = sigmoidf_(p) * scale; }
        }
    }
}

// ============ K2: fused z/za/ya MFMA GEMM (+ Zs_part/zdiag/gate) + scan blocks ============
__global__ __launch_bounds__(256) void k2_gemm3_scan(
    const unsigned short* __restrict__ Axb,
    const unsigned short* __restrict__ Wz, const unsigned short* __restrict__ Wza,
    const unsigned short* __restrict__ Wya,
    const float* __restrict__ b_z, const float* __restrict__ b_za, const float* __restrict__ b_ya,
    unsigned short* __restrict__ gateb, float* __restrict__ Zs_part, float* __restrict__ zdiag,
    const float* __restrict__ a_arr, const float* __restrict__ r_arr,
    float* __restrict__ Si, float* __restrict__ Sr, int nby)
{
    __shared__ short As[64 * 32];
    __shared__ short Bs[3][64 * 32];
    __shared__ float red[64][8];
    __shared__ float2 buf[2][256];
    const int tid = threadIdx.x;

    if ((int)blockIdx.y >= nby) {
        // ---------- scan block: inclusive cumsum over l for one (b,h) ----------
        const int u = ((int)blockIdx.y - nby) * 8 + (int)blockIdx.x;
        const int b = u >> 3, h = u & 7;
        float2 v[4];
        float2 run = make_float2(0.f, 0.f);
        const size_t base = ((size_t)b * L_ + tid * 4) * H_ + h;
#pragma unroll
        for (int j = 0; j < 4; ++j) {
            run.x += a_arr[base + j * H_];
            run.y += r_arr[base + j * H_];
            v[j] = run;
        }
        buf[0][tid] = run;
        __syncthreads();
        int src = 0;
        for (int off = 1; off < 256; off <<= 1) {
            float2 val = buf[src][tid];
            if (tid >= off) { float2 p = buf[src][tid - off]; val.x += p.x; val.y += p.y; }
            buf[src ^ 1][tid] = val;
            src ^= 1;
            __syncthreads();
        }
        float2 excl = make_float2(0.f, 0.f);
        if (tid > 0) excl = buf[src][tid - 1];
#pragma unroll
        for (int j = 0; j < 4; ++j) {
            Si[base + j * H_] = v[j].x + excl.x;
            Sr[base + j * H_] = -(v[j].y + excl.y);
        }
        return;
    }

    // ---------- GEMM path ----------
    const int lane = tid & 63, w = tid >> 6;
    const int wm = w >> 1, wn = w & 1;
    const int bx = blockIdx.x;                 // == head h (BN=64=I, N=512)
    const int row0 = blockIdx.y * 64, col0 = bx * 64;

    const f32x4 zf = {0.f, 0.f, 0.f, 0.f};
    f32x4 accz[2][2], accza[2][2], accya[2][2];
#pragma unroll
    for (int a = 0; a < 2; ++a)
#pragma unroll
        for (int bq = 0; bq < 2; ++bq) { accz[a][bq] = zf; accza[a][bq] = zf; accya[a][bq] = zf; }

    const int sr = tid >> 2, sc = tid & 3;
    const int sld = sr * 64 + ((sc ^ ((sr >> 1) & 3)) << 4);   // swizzled LDS byte offset
    const size_t gA = (size_t)(row0 + sr) * 512 + sc * 8;
    const size_t gB = (size_t)(col0 + sr) * 512 + sc * 8;

    for (int k0 = 0; k0 < 512; k0 += 32) {
        *(int4*)((char*)As + sld)    = *(const int4*)(Axb + gA + k0);
        *(int4*)((char*)Bs[0] + sld) = *(const int4*)(Wz  + gB + k0);
        *(int4*)((char*)Bs[1] + sld) = *(const int4*)(Wza + gB + k0);
        *(int4*)((char*)Bs[2] + sld) = *(const int4*)(Wya + gB + k0);
        __syncthreads();
        short8 af[2], bz[2], bza[2], bya[2];
#pragma unroll
        for (int fi = 0; fi < 2; ++fi) {
            int rr = wm * 32 + fi * 16 + (lane & 15);
            int off = rr * 64 + ((((lane >> 4)) ^ ((rr >> 1) & 3)) << 4);
            af[fi] = *(const short8*)((const char*)As + off);
        }
#pragma unroll
        for (int fj = 0; fj < 2; ++fj) {
            int rr = wn * 32 + fj * 16 + (lane & 15);
            int off = rr * 64 + ((((lane >> 4)) ^ ((rr >> 1) & 3)) << 4);
            bz[fj]  = *(const short8*)((const char*)Bs[0] + off);
            bza[fj] = *(const short8*)((const char*)Bs[1] + off);
            bya[fj] = *(const short8*)((const char*)Bs[2] + off);
        }
#pragma unroll
        for (int fi = 0; fi < 2; ++fi)
#pragma unroll
            for (int fj = 0; fj < 2; ++fj) {
                accz[fi][fj]  = __builtin_amdgcn_mfma_f32_16x16x32_bf16(af[fi], bz[fj],  accz[fi][fj],  0, 0, 0);
                accza[fi][fj] = __builtin_amdgcn_mfma_f32_16x16x32_bf16(af[fi], bza[fj], accza[fi][fj], 0, 0, 0);
                accya[fi][fj] = __builtin_amdgcn_mfma_f32_16x16x32_bf16(af[fi], bya[fj], accya[fi][fj], 0, 0, 0);
            }
        __syncthreads();
    }

    const bool first = (row0 & (L_ - 1)) == 0;   // rows l in [0,64): contains l<=h and diag
    const int b8 = (row0 >> 10) * 8;
#pragma unroll
    for (int fj = 0; fj < 2; ++fj) {
        float lsum = 0.f;
        int lc = wn * 32 + fj * 16 + (lane & 15);
        int col = col0 + lc;
        float Bz = b_z[col], Bza = b_za[col], Bya = b_ya[col];
#pragma unroll
        for (int fi = 0; fi < 2; ++fi) {
#pragma unroll
            for (int q = 0; q < 4; ++q) {
                int lr = wm * 32 + fi * 16 + ((lane >> 4) << 2) + q;
                int row = row0 + lr;
                float pz = accz[fi][fj][q] + Bz;
                float pza = accza[fi][fj][q] + Bza;
                float v = pz * siluf_(pza);
                gateb[(size_t)row * 512 + col] = f2bf(siluf_(accya[fi][fj][q] + Bya));
                if (!first || lr > bx) lsum += v;
                if (first && lr == bx) zdiag[(b8 + bx) * 64 + lc] = v;
            }
        }
        red[lc][wm * 4 + (lane >> 4)] = lsum;
    }
    __syncthreads();
    if (tid < 64) {
        float s = 0.f;
#pragma unroll
        for (int j = 0; j < 8; ++j) s += red[tid][j];
        Zs_part[((size_t)blockIdx.y * 8 + bx) * 64 + tid] = s;   // race-free partials
    }
}

// ============ K3: inline hgn (Zs reduce + h + GroupNorm -> LDS bf16) + gemm_y ============
// 512 threads, 8 waves (2 row-halves x 4 col-quarters). Tile 64x64.
__global__ __launch_bounds__(512) void k3_hgn_gemm_y(
    const unsigned short* __restrict__ Wy, const float* __restrict__ b_y,
    const unsigned short* __restrict__ gateb,
    const float* __restrict__ Sr, const float* __restrict__ Si,
    const float* __restrict__ Zs_part, const float* __restrict__ zdiag,
    const float* __restrict__ lc_r, const float* __restrict__ lc_i,
    const float* __restrict__ gn_w, const float* __restrict__ gn_b,
    float* __restrict__ y)
{
    __shared__ unsigned short hA[64][520];          // 1040B row stride: 16B-aligned, bank-spread
    __shared__ short Bs[64 * 32];
    __shared__ float Cr[8][65], Ci[8][65], Zd[8][65];
    const int tid = threadIdx.x;
    const int row0 = blockIdx.y * 64, col0 = blockIdx.x * 64;
    const int b = row0 >> 10;                       // L_=1024

    // ---- stage per-(h,i) constants: Zs (reduced from partials) + lc, zdiag ----
    {
        int h = tid >> 6, i = tid & 63;
        float s = 0.f;
#pragma unroll
        for (int rb = 0; rb < 16; ++rb)
            s += Zs_part[(((size_t)b * 16 + rb) * 8 + h) * 64 + i];
        Cr[h][i] = s + lc_r[h * 64 + i];
        Ci[h][i] = lc_i[h * 64 + i];
        Zd[h][i] = zdiag[((size_t)b * 8 + h) * 64 + i];
    }
    __syncthreads();

    // ---- phase 1: h + GroupNorm, one (row, head) per thread, write bf16 into hA ----
    {
        const int r = tid >> 3, h = tid & 7;
        const int row = row0 + r;
        const float sr = Sr[(size_t)row * 8 + h];
        const float si = Si[(size_t)row * 8 + h];
        const float er = expf(sr);
        const float ca = er * cosf(si), sb = er * sinf(si);
        float sum = 0.f, sq = 0.f;
#pragma unroll 8
        for (int i = 0; i < 64; ++i) {
            float hv = Zd[h][i] + ca * Cr[h][i] - sb * Ci[h][i];
            sum += hv; sq += hv * hv;
        }
        const float mean = sum * (1.f / 64.f);
        const float inv = rsqrtf(sq * (1.f / 64.f) - mean * mean + 1e-5f);
        const float gw = gn_w[h] * inv;
        const float gb = gn_b[h] - mean * gw;
#pragma unroll
        for (int s8 = 0; s8 < 8; ++s8) {
            short8 pk;
#pragma unroll
            for (int j = 0; j < 8; ++j) {
                int i = s8 * 8 + j;
                float hv = Zd[h][i] + ca * Cr[h][i] - sb * Ci[h][i];
                pk[j] = (short)f2bf(hv * gw + gb);
            }
            int slot = (s8 + h) & 7;   // per-head slot rotation: conflict-free writes
            *(short8*)((char*)&hA[r][0] + h * 128 + slot * 16) = pk;
        }
    }
    __syncthreads();

    // ---- phase 2: y = (hA @ Wy^T(bf16) + b_y) * gate ----
    const int lane = tid & 63, w = tid >> 6;
    const int wm = w >> 2, wn = w & 3;
    const f32x4 zf = {0.f, 0.f, 0.f, 0.f};
    f32x4 acc[2] = {zf, zf};

    const int brow = tid >> 3, bsc = tid & 7;      // B staging: 64 rows x 8 chunks of 8B
    const size_t gB = (size_t)(col0 + brow) * 512 + bsc * 4;
    const int bwr = brow * 64 + (((bsc >> 1) ^ ((brow >> 1) & 3)) << 4) + (bsc & 1) * 8;

    for (int k0 = 0; k0 < 512; k0 += 32) {
        *(int2*)((char*)Bs + bwr) = *(const int2*)(Wy + gB + k0);
        __syncthreads();
        short8 af[2], bf;
        const int hk = k0 >> 6;
        const int t = ((k0 & 32) >> 3) + (lane >> 4);
        const int slot = (t + hk) & 7;             // undo phase-1 rotation
#pragma unroll
        for (int fi = 0; fi < 2; ++fi) {
            int rr = wm * 32 + fi * 16 + (lane & 15);
            af[fi] = *(const short8*)((const char*)&hA[rr][0] + hk * 128 + slot * 16);
        }
        {
            int rr = wn * 16 + (lane & 15);
            bf = *(const short8*)((const char*)Bs + rr * 64 + (((lane >> 4) ^ ((rr >> 1) & 3)) << 4));
        }
        acc[0] = __builtin_amdgcn_mfma_f32_16x16x32_bf16(af[0], bf, acc[0], 0, 0, 0);
        acc[1] = __builtin_amdgcn_mfma_f32_16x16x32_bf16(af[1], bf, acc[1], 0, 0, 0);
        __syncthreads();
    }

    const int col = col0 + wn * 16 + (lane & 15);
    const float By = b_y[col];
#pragma unroll
    for (int fi = 0; fi < 2; ++fi)
#pragma unroll
        for (int q = 0; q < 4; ++q) {
            int row = row0 + wm * 32 + fi * 16 + ((lane >> 4) << 2) + q;
            size_t idx = (size_t)row * 512 + col;
            y[idx] = (acc[fi][q] + By) * bf2f(gateb[idx]);
        }
}

extern "C" void kernel_launch(void* const* d_in, const int* in_sizes, int n_in,
                              void* d_out, int out_size, void* d_ws, size_t ws_size,
                              hipStream_t stream) {
    (void)n_in; (void)out_size; (void)ws_size;
    const float* x     = (const float*)d_in[0];
    const float* w_z   = (const float*)d_in[1];
    const float* b_z   = (const float*)d_in[2];
    const float* w_za  = (const float*)d_in[3];
    const float* b_za  = (const float*)d_in[4];
    const float* w_ang = (const float*)d_in[5];
    const float* b_ang = (const float*)d_in[6];
    const float* w_abs = (const float*)d_in[7];
    const float* b_abs = (const float*)d_in[8];
    const float* w_y   = (const float*)d_in[9];
    const float* b_y   = (const float*)d_in[10];
    const float* w_ya  = (const float*)d_in[11];
    const float* b_ya  = (const float*)d_in[12];
    const float* gn_w  = (const float*)d_in[13];
    const float* gn_b  = (const float*)d_in[14];
    const float* lc_r  = (const float*)d_in[15];
    const float* lc_i  = (const float*)d_in[16];
    float* y = (float*)d_out;

    const int BL = in_sizes[0] / D_;   // 2048
    const int B  = BL / L_;            // 2

    unsigned short* xb   = (unsigned short*)d_ws;            // BL*512
    unsigned short* wtz  = xb   + (size_t)BL * 512;          // 512*512 each
    unsigned short* wtza = wtz  + 512 * 512;
    unsigned short* wtya = wtza + 512 * 512;
    unsigned short* wty  = wtya + 512 * 512;
    unsigned short* gateb= wty  + 512 * 512;                 // BL*512
    float* a_arr = (float*)(gateb + (size_t)BL * 512);       // BL*H
    float* r_arr = a_arr + (size_t)BL * H_;
    float* Si    = r_arr + (size_t)BL * H_;
    float* Sr    = Si    + (size_t)BL * H_;
    float* zdiag = Sr    + (size_t)BL * H_;                  // B*H*I
    float* Zs_part = zdiag + (size_t)B * H_ * I_;            // (BL/64)*H*I

    const int nconv = (BL * 512) / 1024;    // 1024
    const int nby = BL / 64;                // 32

    k1_prep<<<nconv + 256 + BL / 4, 256, 0, stream>>>(
        x, xb, nconv, w_z, w_za, w_ya, w_y, wtz, wtza, wtya, wty,
        w_ang, b_ang, w_abs, b_abs, a_arr, r_arr);
    k2_gemm3_scan<<<dim3(8, nby + 2), 256, 0, stream>>>(
        xb, wtz, wtza, wtya, b_z, b_za, b_ya,
        gateb, Zs_part, zdiag, a_arr, r_arr, Si, Sr, nby);
    k3_hgn_gemm_y<<<dim3(8, nby), 512, 0, stream>>>(
        wty, b_y, gateb, Sr, Si, Zs_part, zdiag, lc_r, lc_i, gn_w, gn_b, y);
}